// Round 13
// baseline (347.769 us; speedup 1.0000x reference)
//
#include <hip/hip_runtime.h>

#define NODES   65536      // B*N
#define NGRAPH  512        // N
#define BATCH   128        // B
#define HID     128
#define TOUT    12
#define MAXDEG  10
#define NDEG    11
#define EPSV    1e-5f
#define MT      64                 // nodes per conv tile
#define NTILES  (NODES / MT + NDEG)   // 1035
#define PCAP    1056                  // partials rows capacity (mult of 4)

typedef float f32x4 __attribute__((ext_vector_type(4)));

__device__ __forceinline__ f32x4 ntload(const float* p) {
    return __builtin_nontemporal_load((const f32x4*)p);
}
__device__ __forceinline__ void ntstore(float* p, f32x4 v) {
    __builtin_nontemporal_store(v, (f32x4*)p);
}
__device__ __forceinline__ f32x4 bnrelu4(f32x4 v, f32x4 sc, f32x4 sh) {
    f32x4 r;
    r.x = fmaxf(fmaf(v.x, sc.x, sh.x), 0.f);
    r.y = fmaxf(fmaf(v.y, sc.y, sh.y), 0.f);
    r.z = fmaxf(fmaf(v.z, sc.z, sh.z), 0.f);
    r.w = fmaxf(fmaf(v.w, sc.w, sh.w), 0.f);
    return r;
}

// ---------------------------------------------------------------- zero state
__global__ void k_zero(f32x4* part4, float* stats1, float* stats2, int* cnt) {
    int i = blockIdx.x * 256 + threadIdx.x;       // grid PCAP/4
    part4[i] = 0.f;
    if (blockIdx.x == 0) {
        stats1[threadIdx.x] = 0.f;
        stats2[threadIdx.x] = 0.f;
        if (threadIdx.x < 16) cnt[threadIdx.x] = 0;
    }
}

// ---------------------------------------------------------------- bucket nodes by degree
__global__ void k_bucket(const int* __restrict__ deg, int* __restrict__ cnt,
                         int* __restrict__ lists) {
    __shared__ int s_cnt[NDEG];
    __shared__ int s_base[NDEG];
    int t = threadIdx.x;
    if (t < NDEG) s_cnt[t] = 0;
    __syncthreads();
    int i = blockIdx.x * 256 + t;
    int d = deg[i];
    d = d < 0 ? 0 : (d > MAXDEG ? MAXDEG : d);
    int pos = atomicAdd(&s_cnt[d], 1);
    __syncthreads();
    if (t < NDEG) s_base[t] = atomicAdd(&cnt[t], s_cnt[t]);
    __syncthreads();
    lists[d * NODES + s_base[d] + pos] = i;
}

// ---------------------------------------------------------------- tile table
__global__ void k_plan(const int* __restrict__ cnt, int* __restrict__ offs) {
    if (threadIdx.x == 0) {
        int acc = 0;
        offs[0] = 0;
        for (int d = 0; d < NDEG; ++d) {
            acc += (cnt[d] + MT - 1) / MT;
            offs[d + 1] = acc;
        }
    }
}

// ---------------------------------------------------------------- build concatenated weights/biases
__global__ void k_build1(const float* __restrict__ Ws, const float* __restrict__ Wn,
                         float* __restrict__ Wcat) {
    int idx = blockIdx.x * 256 + threadIdx.x;     // grid 220
    int h4 = idx & 31;
    int k  = (idx >> 5) % 160;
    int d  = idx / (160 * 32);
    f32x4 v = 0.f;
    if (k < 75)
        v = *(const f32x4*)(Ws + ((size_t)d * 75 + k) * 128 + h4 * 4);
    else if (k >= 80 && k < 155 && d >= 1)
        v = *(const f32x4*)(Wn + ((size_t)(d - 1) * 75 + (k - 80)) * 128 + h4 * 4);
    *(f32x4*)(Wcat + ((size_t)d * 160 + k) * 128 + h4 * 4) = v;
}
__global__ void k_build2(const float* __restrict__ Ws, const float* __restrict__ Wn,
                         float* __restrict__ Wcat) {
    int idx = blockIdx.x * 256 + threadIdx.x;     // grid 352
    int h4 = idx & 31;
    int k  = (idx >> 5) & 255;
    int d  = idx >> 13;
    f32x4 v = 0.f;
    if (k < 128)
        v = *(const f32x4*)(Ws + ((size_t)d * 128 + k) * 128 + h4 * 4);
    else if (d >= 1)
        v = *(const f32x4*)(Wn + ((size_t)(d - 1) * 128 + (k - 128)) * 128 + h4 * 4);
    *(f32x4*)(Wcat + ((size_t)d * 256 + k) * 128 + h4 * 4) = v;
}
__global__ void k_bias(const float* bs1, const float* bn1, const float* bs2, const float* bn2,
                       float* bcat1, float* bcat2) {
    int d = blockIdx.x, t = threadIdx.x;          // 11 x 256
    if (t < 128) bcat1[d * 128 + t] = bs1[d * 128 + t] + (d > 0 ? bn1[(d - 1) * 128 + t] : 0.f);
    else { int h = t - 128; bcat2[d * 128 + h] = bs2[d * 128 + h] + (d > 0 ? bn2[(d - 1) * 128 + h] : 0.f); }
}

// ---------------------------------------------------------------- layer-1 pack: feats1[node][160] = [x(75)|0(5)|ns1(80)]
__global__ void k_ns1(const float* __restrict__ x, const int* __restrict__ adj,
                      const int* __restrict__ deg, float* __restrict__ feats1) {
    int idx = blockIdx.x * 256 + threadIdx.x;     // grid 5120
    int node = idx / 20;
    int q = idx - node * 20;
    int f = q * 4;
    int d = deg[node];
    d = d < 0 ? 0 : (d > MAXDEG ? MAXDEG : d);
    const int* arow = adj + node * MAXDEG;
    int base = node & ~(NGRAPH - 1);
    f32x4 s = 0.f;
    for (int k = 0; k < d; ++k) {
        const float* xr = x + (size_t)(base + arow[k]) * 75 + f;
        if (f + 3 < 75) { s.x += xr[0]; s.y += xr[1]; s.z += xr[2]; s.w += xr[3]; }
        else {
            if (f + 0 < 75) s.x += xr[0];
            if (f + 1 < 75) s.y += xr[1];
            if (f + 2 < 75) s.z += xr[2];
        }
    }
    *(f32x4*)(feats1 + (size_t)node * 160 + 80 + f) = s;
    f32x4 v = 0.f;
    const float* xs = x + (size_t)node * 75 + f;
    if (f + 3 < 75) { v.x = xs[0]; v.y = xs[1]; v.z = xs[2]; v.w = xs[3]; }
    else {
        if (f + 0 < 75) v.x = xs[0];
        if (f + 1 < 75) v.y = xs[1];
        if (f + 2 < 75) v.z = xs[2];
    }
    *(f32x4*)(feats1 + (size_t)node * 160 + f) = v;
}

// ---------------------------------------------------------------- BN1 scale/shift from stats
__global__ void k_scale(const float* __restrict__ stats, const float* __restrict__ g,
                        const float* __restrict__ be, float* __restrict__ sc,
                        float* __restrict__ sh) {
    int c = threadIdx.x;              // 128
    const float inv = 1.f / (float)NODES;
    float mu  = stats[c] * inv;
    float var = stats[HID + c] * inv - mu * mu;
    float rs  = rsqrtf(var + EPSV);
    float s   = g[c] * rs;
    sc[c] = s;
    sh[c] = be[c] - mu * s;
}

// ---------------------------------------------------------------- layer-2 gather with fused BN1+ReLU
__global__ void k_ns2(const float* __restrict__ h1, const int* __restrict__ adj,
                      const int* __restrict__ deg, const float* __restrict__ sc,
                      const float* __restrict__ sh, float* __restrict__ ns2) {
    int idx = blockIdx.x * 256 + threadIdx.x;     // grid 8192
    int node = idx >> 5;
    int f = (idx & 31) * 4;
    int d = deg[node];
    d = d < 0 ? 0 : (d > MAXDEG ? MAXDEG : d);
    const int* arow = adj + node * MAXDEG;
    int base = node & ~(NGRAPH - 1);
    f32x4 sc4 = *(const f32x4*)(sc + f);
    f32x4 sh4 = *(const f32x4*)(sh + f);
    f32x4 s = 0.f;
    for (int k = 0; k < d; ++k) {
        f32x4 v = *(const f32x4*)(h1 + (size_t)(base + arow[k]) * HID + f);
        s += bnrelu4(v, sc4, sh4);
    }
    *(f32x4*)(ns2 + (size_t)node * HID + f) = s;
}

// ---------------------------------------------------------------- conv: grouped GEMM, wave-column-slab partition
// Block: 64 nodes x 128 cols, 256 thr (4 waves). Wave w owns cols w*32..+31 x all 64 rows;
// thread: 8 rows x 4 cols. K chunked by 16, reg-prefetch dbuf (~25 KB -> 6 blocks/CU).
// Per wave-k LDS: W 128 B conflict-free (8 b128 covering 32 banks) + F 256 B 2-way.
template<int S, bool BN>
__global__ __launch_bounds__(256, 6)
void k_conv(const float* __restrict__ f160, const float* __restrict__ h1,
            const float* __restrict__ ns2, const float* __restrict__ Wcat,
            const float* __restrict__ bcat, const float* __restrict__ sc,
            const float* __restrict__ sh, const int* __restrict__ lists,
            const int* __restrict__ cnt, const int* __restrict__ offs,
            float* __restrict__ out, float* __restrict__ partials) {
    constexpr int NCH = S / 16;

    __shared__ int   s_ids[MT];
    __shared__ float sW[2][16][128];
    __shared__ float sF[2][16][68];    // transposed: sF[k][row]; stride 68 -> 2-way stores (free)

    const int bid = blockIdx.x;
    if (bid >= offs[NDEG]) return;
    int d = 0;
    #pragma unroll
    for (int q = 1; q < NDEG; ++q) d += (bid >= offs[q]);
    const int c  = cnt[d];
    const int m0 = (bid - offs[d]) * MT;
    const int mv = min(MT, c - m0);
    const int t  = threadIdx.x;

    if (t < MT) s_ids[t] = lists[d * NODES + m0 + (t < mv ? t : 0)];
    __syncthreads();

    // staging roles (as r11: W 2 rows/thread, F 1 b128/thread)
    const int kw = t >> 5;             // W rows kw, kw+8
    const int c4 = t & 31;             // W col quad
    const int fr = t >> 2;             // F row 0..63
    const int kq = t & 3;              // F k quad within chunk
    const float* Wbase = Wcat + (size_t)d * S * 128;
    const int fid = s_ids[fr];
    const float* Frow1 = (S == 160) ? (f160 + (size_t)fid * 160) : nullptr;
    const float* FrowS = (S == 256) ? (h1 + (size_t)fid * 128) : nullptr;
    const float* FrowN = (S == 256) ? (ns2 + (size_t)fid * 128) : nullptr;

    f32x4 w0, w1, f0;
    auto LOAD = [&](int ch) {
        const float* wp = Wbase + (size_t)(ch * 16 + kw) * 128 + c4 * 4;
        w0 = *(const f32x4*)(wp);
        w1 = *(const f32x4*)(wp + 8 * 128);
        if constexpr (S == 160) {
            f0 = ntload(Frow1 + ch * 16 + kq * 4);
        } else {
            if (ch < 8) {
                int cc = ch * 16 + kq * 4;
                f0 = ntload(FrowS + cc);
                if constexpr (BN)
                    f0 = bnrelu4(f0, *(const f32x4*)(sc + cc), *(const f32x4*)(sh + cc));
            } else {
                f0 = ntload(FrowN + (ch - 8) * 16 + kq * 4);
            }
        }
    };
    auto STORE = [&](int buf) {
        *(f32x4*)&sW[buf][kw][c4 * 4]     = w0;
        *(f32x4*)&sW[buf][kw + 8][c4 * 4] = w1;
        sF[buf][kq * 4 + 0][fr] = f0.x;
        sF[buf][kq * 4 + 1][fr] = f0.y;
        sF[buf][kq * 4 + 2][fr] = f0.z;
        sF[buf][kq * 4 + 3][fr] = f0.w;
    };

    // compute mapping: wave-column slabs
    const int wave = t >> 6;
    const int lane = t & 63;
    const int ccg  = lane & 7;         // col group within wave
    const int rrg  = lane >> 3;        // row group 0..7
    const int colb = wave * 32 + ccg * 4;
    const int rowb = rrg * 8;

    f32x4 acc[8];
    {
        f32x4 b = *(const f32x4*)(bcat + d * HID + colb);
        #pragma unroll
        for (int j = 0; j < 8; ++j) acc[j] = b;
    }

    LOAD(0); STORE(0);
    __syncthreads();

    for (int ch = 0; ch < NCH; ++ch) {
        const int buf = ch & 1;
        const bool more = (ch + 1 < NCH);
        if (more) LOAD(ch + 1);        // issue early; LDS-write after compute
        #pragma unroll 8
        for (int k = 0; k < 16; ++k) {
            f32x4 wv = *(const f32x4*)&sW[buf][k][colb];
            f32x4 fA = *(const f32x4*)&sF[buf][k][rowb];
            f32x4 fB = *(const f32x4*)&sF[buf][k][rowb + 4];
            acc[0] += fA.x * wv;
            acc[1] += fA.y * wv;
            acc[2] += fA.z * wv;
            acc[3] += fA.w * wv;
            acc[4] += fB.x * wv;
            acc[5] += fB.y * wv;
            acc[6] += fB.z * wv;
            acc[7] += fB.w * wv;
        }
        if (more) STORE(buf ^ 1);      // safe: all waves past barrier of prev iter
        __syncthreads();
    }

    // epilogue: NT store (aligned 128B segments per row per wave) + BN partials
    f32x4 cs = 0.f, cq = 0.f;
    #pragma unroll
    for (int j = 0; j < 8; ++j) {
        int i = rowb + j;
        if (i < mv) {
            ntstore(out + (size_t)s_ids[i] * HID + colb, acc[j]);
            cs += acc[j];
            cq += acc[j] * acc[j];
        }
    }
    __syncthreads();
    float* red = &sW[0][0][0];         // 8 rrg x 256 floats = 2048 <= 4096
    *(f32x4*)&red[rrg * 256 + colb]       = cs;
    *(f32x4*)&red[rrg * 256 + 128 + colb] = cq;
    __syncthreads();
    {
        float tot = 0.f;
        #pragma unroll
        for (int g = 0; g < 8; ++g) tot += red[g * 256 + t];
        partials[(size_t)bid * 256 + t] = tot;   // bid unique: plain store
    }
}

// ---------------------------------------------------------------- drain BN partials (and re-zero)
__global__ void k_redstats(float* __restrict__ partials, float* __restrict__ stats) {
    int t = threadIdx.x;
    float acc = 0.f;
    for (int bx = blockIdx.x; bx < PCAP; bx += gridDim.x) {
        float* p = partials + (size_t)bx * 256 + t;
        acc += *p;
        *p = 0.f;
    }
    atomicAdd(&stats[t], acc);
}

// ---------------------------------------------------------------- BN2 + ReLU + mean over N + dense
__global__ void k_pool_dense(const float* __restrict__ h2, const float* __restrict__ stats,
                             const float* __restrict__ gamma, const float* __restrict__ beta,
                             const float* __restrict__ Wd, const float* __restrict__ bd,
                             float* __restrict__ outp) {
    __shared__ float s_part[4][HID];
    __shared__ float s_pool[HID];
    const int b = blockIdx.x;
    const int t = threadIdx.x;        // 512
    const int hcol = t & (HID - 1);
    const int q = t >> 7;             // 0..3
    const float inv = 1.f / (float)NODES;
    float mu  = stats[hcol] * inv;
    float var = stats[HID + hcol] * inv - mu * mu;
    float rs  = rsqrtf(var + EPSV);
    float sc  = gamma[hcol] * rs;
    float sh  = beta[hcol] - mu * sc;
    float acc = 0.f;
    const float* hp = h2 + ((size_t)b * NGRAPH + q * 128) * HID + hcol;
    #pragma unroll 4
    for (int n = 0; n < 128; ++n)
        acc += fmaxf(fmaf(hp[(size_t)n * HID], sc, sh), 0.f);
    s_part[q][hcol] = acc;
    __syncthreads();
    if (t < HID)
        s_pool[t] = (s_part[0][t] + s_part[1][t] + s_part[2][t] + s_part[3][t]) * (1.f / NGRAPH);
    __syncthreads();
    if (t < TOUT) {
        float o = bd[t];
        for (int hh = 0; hh < HID; ++hh)
            o = fmaf(s_pool[hh], Wd[hh * TOUT + t], o);
        outp[b * TOUT + t] = o;
    }
}

// ---------------------------------------------------------------- launch
extern "C" void kernel_launch(void* const* d_in, const int* in_sizes, int n_in,
                              void* d_out, int out_size, void* d_ws, size_t ws_size,
                              hipStream_t stream) {
    const float* x   = (const float*)d_in[0];
    const int*   adj = (const int*)d_in[1];
    const int*   deg = (const int*)d_in[2];
    const float* Wn1 = (const float*)d_in[3];
    const float* Ws1 = (const float*)d_in[4];
    const float* bn1 = (const float*)d_in[5];
    const float* bs1 = (const float*)d_in[6];
    const float* g1  = (const float*)d_in[7];
    const float* be1 = (const float*)d_in[8];
    const float* Wn2 = (const float*)d_in[9];
    const float* Ws2 = (const float*)d_in[10];
    const float* bn2 = (const float*)d_in[11];
    const float* bs2 = (const float*)d_in[12];
    const float* g2  = (const float*)d_in[13];
    const float* be2 = (const float*)d_in[14];
    const float* Wd  = (const float*)d_in[15];
    const float* bd  = (const float*)d_in[16];

    float* ws     = (float*)d_ws;
    float* feats1 = ws;                          // 10,485,760 f  [x|pad|ns1], stride 160
    float* h2     = ws;                          // alias: feats1 dead when conv2 writes
    float* h1     = ws + 10485760;               // 8,388,608 f   dense conv1 out (raw)
    float* ns2    = ws + 18874368;               // 8,388,608 f   dense, bnrelu'd-gather sum
    float* Wcat1  = ws + 27262976;               // 225,280
    float* Wcat2  = ws + 27488256;               // 360,448
    float* bcat1  = ws + 27848704;               // 1,408
    float* bcat2  = ws + 27850112;               // 1,408
    float* part   = ws + 27851520;               // 270,336 (PCAP*256)
    float* stats1 = ws + 28121856;               // 256
    float* stats2 = ws + 28122112;               // 256
    float* sc1    = ws + 28122368;               // 128
    float* sh1    = ws + 28122496;               // 128
    int*   cnt    = (int*)(ws + 28122624);       // 16
    int*   offs   = cnt + 16;                    // 16
    int*   lists  = cnt + 32;                    // 720,896 ints -> total ~115.5 MB

    k_zero<<<PCAP / 4, 256, 0, stream>>>((f32x4*)part, stats1, stats2, cnt);
    k_bucket<<<NODES / 256, 256, 0, stream>>>(deg, cnt, lists);
    k_plan<<<1, 64, 0, stream>>>(cnt, offs);
    k_build1<<<220, 256, 0, stream>>>(Ws1, Wn1, Wcat1);
    k_build2<<<352, 256, 0, stream>>>(Ws2, Wn2, Wcat2);
    k_bias<<<NDEG, 256, 0, stream>>>(bs1, bn1, bs2, bn2, bcat1, bcat2);

    // ----- layer 1: pack feats1, conv -> dense raw h1
    k_ns1<<<NODES * 20 / 256, 256, 0, stream>>>(x, adj, deg, feats1);
    k_conv<160, false><<<NTILES, 256, 0, stream>>>(feats1, nullptr, nullptr, Wcat1, bcat1,
                                                   nullptr, nullptr, lists, cnt, offs,
                                                   h1, part);
    k_redstats<<<32, 256, 0, stream>>>(part, stats1);
    k_scale<<<1, 128, 0, stream>>>(stats1, g1, be1, sc1, sh1);

    // ----- layer 2: fused-BN gather -> ns2, conv (BN on self cols) -> h2
    k_ns2<<<8192, 256, 0, stream>>>(h1, adj, deg, sc1, sh1, ns2);
    k_conv<256, true><<<NTILES, 256, 0, stream>>>(nullptr, h1, ns2, Wcat2, bcat2,
                                                  sc1, sh1, lists, cnt, offs,
                                                  h2, part);
    k_redstats<<<32, 256, 0, stream>>>(part, stats2);

    // ----- BN2 + ReLU + pool + dense
    k_pool_dense<<<BATCH, 512, 0, stream>>>(h2, stats2, g2, be2, Wd, bd, (float*)d_out);
}